// Round 1
// baseline (4403.647 us; speedup 1.0000x reference)
//
#include <hip/hip_runtime.h>

// Problem constants (from reference): B=64, S=256, DIM=512, Q=8, K=1024
#define NROWS   16384          // B*S
#define DIM     512
#define QQ      8
#define KK      1024
#define QOUT_SZ (NROWS * DIM)  // 8388608
#define IDX_SZ  (NROWS * QQ)   // 131072

// argmin tiling
#define BR 32    // rows per block
#define BC 128   // codes per tile
#define DC 32    // d-chunk

// ---------------- ws layout ----------------
// [0]                double loss
// [16]               int    idx[NROWS]
// [16+64K]           float  rnorm[NROWS]
// [16+64K+64K]       float  enorm[QQ*KK]
// [16+64K+64K+32K+pad] float res[NROWS*DIM]
#define WS_LOSS_OFF   0
#define WS_IDX_OFF    16
#define WS_RNORM_OFF  (WS_IDX_OFF + NROWS * 4)
#define WS_ENORM_OFF  (WS_RNORM_OFF + NROWS * 4)
#define WS_RES_OFF    ((WS_ENORM_OFF + QQ * KK * 4 + 15) & ~15)

__global__ void k_zero_loss(double* loss) { *loss = 0.0; }

// res = x, rnorm[row] = sum(x^2). 4 rows/block (wave per row).
__global__ __launch_bounds__(256) void k_init(const float4* __restrict__ x4,
                                              float4* __restrict__ res4,
                                              float* __restrict__ rnorm) {
    int row  = blockIdx.x * 4 + (threadIdx.x >> 6);
    int lane = threadIdx.x & 63;
    float s = 0.f;
#pragma unroll
    for (int i = 0; i < 2; i++) {
        int c = lane + i * 64;            // 128 float4 per row
        float4 v = x4[row * (DIM / 4) + c];
        res4[row * (DIM / 4) + c] = v;
        s += v.x * v.x + v.y * v.y + v.z * v.z + v.w * v.w;
    }
#pragma unroll
    for (int off = 32; off; off >>= 1) s += __shfl_down(s, off, 64);
    if (lane == 0) rnorm[row] = s;
}

// enorm[qk] = sum(embed_row^2) over all QQ*KK rows. 4 rows/block.
__global__ __launch_bounds__(256) void k_enorm(const float4* __restrict__ e4,
                                               float* __restrict__ enorm) {
    int row  = blockIdx.x * 4 + (threadIdx.x >> 6);   // 0..8191
    int lane = threadIdx.x & 63;
    float s = 0.f;
#pragma unroll
    for (int i = 0; i < 2; i++) {
        int c = lane + i * 64;
        float4 v = e4[row * (DIM / 4) + c];
        s += v.x * v.x + v.y * v.y + v.z * v.z + v.w * v.w;
    }
#pragma unroll
    for (int off = 32; off; off >>= 1) s += __shfl_down(s, off, 64);
    if (lane == 0) enorm[row] = s;
}

// Distance GEMM + row-argmin for one quantizer step.
// Block: 32 rows x all 1024 codes (8 tiles of 128). 256 threads:
//   rg = tid>>5 (0..7) owns rows rg*4..+3 ; cg = tid&31 owns codes cg*4..+3 in tile.
__global__ __launch_bounds__(256) void k_argmin(const float* __restrict__ res,
                                                const float* __restrict__ embed,   // [KK][DIM], this quantizer
                                                const float* __restrict__ enorm,   // [KK], this quantizer
                                                const float* __restrict__ rnorm,
                                                int* __restrict__ idx_out) {
    __shared__ float es[DC * BC];   // [dd][c]  (transposed for b128 reads)
    __shared__ float xs[DC * BR];   // [dd][r]

    const int tid = threadIdx.x;
    const int rowbase = blockIdx.x * BR;
    const int rg = tid >> 5;
    const int cg = tid & 31;
    const int r0 = rg * 4;

    float rn[4];
#pragma unroll
    for (int i = 0; i < 4; i++) rn[i] = rnorm[rowbase + r0 + i];

    float bestd[4];
    int   bestk[4];
#pragma unroll
    for (int i = 0; i < 4; i++) { bestd[i] = 3.4e38f; bestk[i] = 0; }

    for (int ct = 0; ct < KK / BC; ct++) {
        float acc[4][4];
#pragma unroll
        for (int i = 0; i < 4; i++)
#pragma unroll
            for (int j = 0; j < 4; j++) acc[i][j] = 0.f;

        for (int dt = 0; dt < DIM / DC; dt++) {
            __syncthreads();
            // stage embed tile: 128 codes x 32 d = 1024 float4, 4 per thread
#pragma unroll
            for (int p = 0; p < 4; p++) {
                int lin = p * 256 + tid;       // 0..1023
                int kl  = lin >> 3;            // 0..127
                int dp  = (lin & 7) * 4;       // 0,4,..,28
                const float4 v = *(const float4*)&embed[(ct * BC + kl) * DIM + dt * DC + dp];
                es[(dp + 0) * BC + kl] = v.x;
                es[(dp + 1) * BC + kl] = v.y;
                es[(dp + 2) * BC + kl] = v.z;
                es[(dp + 3) * BC + kl] = v.w;
            }
            // stage residual tile: 32 rows x 32 d = 256 float4, 1 per thread
            {
                int rl = tid >> 3;
                int dp = (tid & 7) * 4;
                const float4 v = *(const float4*)&res[(rowbase + rl) * DIM + dt * DC + dp];
                xs[(dp + 0) * BR + rl] = v.x;
                xs[(dp + 1) * BR + rl] = v.y;
                xs[(dp + 2) * BR + rl] = v.z;
                xs[(dp + 3) * BR + rl] = v.w;
            }
            __syncthreads();

#pragma unroll
            for (int dd = 0; dd < DC; dd++) {
                const float4 ev = *(const float4*)&es[dd * BC + (cg << 2)];
                const float4 xv = *(const float4*)&xs[dd * BR + r0];
                acc[0][0] += xv.x * ev.x; acc[0][1] += xv.x * ev.y;
                acc[0][2] += xv.x * ev.z; acc[0][3] += xv.x * ev.w;
                acc[1][0] += xv.y * ev.x; acc[1][1] += xv.y * ev.y;
                acc[1][2] += xv.y * ev.z; acc[1][3] += xv.y * ev.w;
                acc[2][0] += xv.z * ev.x; acc[2][1] += xv.z * ev.y;
                acc[2][2] += xv.z * ev.z; acc[2][3] += xv.z * ev.w;
                acc[3][0] += xv.w * ev.x; acc[3][1] += xv.w * ev.y;
                acc[3][2] += xv.w * ev.z; acc[3][3] += xv.w * ev.w;
            }
        }

        // fold this code-tile into running best (ascending k, strict < => first-min wins)
#pragma unroll
        for (int i = 0; i < 4; i++) {
#pragma unroll
            for (int j = 0; j < 4; j++) {
                int k  = ct * BC + (cg << 2) + j;
                float d = (rn[i] + enorm[k]) - 2.0f * acc[i][j];
                if (d < bestd[i]) { bestd[i] = d; bestk[i] = k; }
            }
        }
    }

    // reduce across 32 cg lanes (same half-wave); lexicographic (d, k) min
#pragma unroll
    for (int m = 1; m < 32; m <<= 1) {
#pragma unroll
        for (int i = 0; i < 4; i++) {
            float od = __shfl_xor(bestd[i], m, 64);
            int   ok = __shfl_xor(bestk[i], m, 64);
            if (od < bestd[i] || (od == bestd[i] && ok < bestk[i])) {
                bestd[i] = od; bestk[i] = ok;
            }
        }
    }
    if (cg == 0) {
#pragma unroll
        for (int i = 0; i < 4; i++) idx_out[rowbase + r0 + i] = bestk[i];
    }
}

// residual update + loss + rnorm + index write. 4 rows/block (wave per row).
// Mirrors reference fp ops: t = q - r; q_st = r + t; new_r = r - q_st; loss += t^2.
__global__ __launch_bounds__(256) void k_update(float* __restrict__ res,
                                                const float* __restrict__ embed,  // this quantizer
                                                const int* __restrict__ idx,
                                                float* __restrict__ rnorm,
                                                double* __restrict__ loss,
                                                float* __restrict__ out_idx,
                                                int q) {
    int row  = blockIdx.x * 4 + (threadIdx.x >> 6);
    int lane = threadIdx.x & 63;
    int k = idx[row];
    const float4* e4 = (const float4*)&embed[k * DIM];
    float4* r4 = (float4*)&res[row * DIM];
    float s_loss = 0.f, s_rn = 0.f;
#pragma unroll
    for (int i = 0; i < 2; i++) {
        int c = lane + i * 64;
        float4 rv = r4[c];
        float4 ev = e4[c];
        float tx = ev.x - rv.x, ty = ev.y - rv.y, tz = ev.z - rv.z, tw = ev.w - rv.w;
        float4 qst = make_float4(rv.x + tx, rv.y + ty, rv.z + tz, rv.w + tw);
        float4 nv  = make_float4(rv.x - qst.x, rv.y - qst.y, rv.z - qst.z, rv.w - qst.w);
        r4[c] = nv;
        s_loss += tx * tx + ty * ty + tz * tz + tw * tw;
        s_rn   += nv.x * nv.x + nv.y * nv.y + nv.z * nv.z + nv.w * nv.w;
    }
#pragma unroll
    for (int off = 32; off; off >>= 1) {
        s_loss += __shfl_down(s_loss, off, 64);
        s_rn   += __shfl_down(s_rn, off, 64);
    }
    if (lane == 0) {
        rnorm[row] = s_rn;
        atomicAdd(loss, (double)s_loss);
        out_idx[row * QQ + q] = (float)k;
    }
}

// qout = x - res_final ; write loss scalar
__global__ __launch_bounds__(256) void k_final(const float4* __restrict__ x4,
                                               const float4* __restrict__ res4,
                                               float4* __restrict__ out4,
                                               const double* __restrict__ loss,
                                               float* __restrict__ out_scalar) {
    int i = blockIdx.x * 256 + threadIdx.x;   // over QOUT_SZ/4
    float4 a = x4[i], b = res4[i];
    out4[i] = make_float4(a.x - b.x, a.y - b.y, a.z - b.z, a.w - b.w);
    if (i == 0) out_scalar[0] = (float)((*loss) * 2.0 / (double)QOUT_SZ);
}

extern "C" void kernel_launch(void* const* d_in, const int* in_sizes, int n_in,
                              void* d_out, int out_size, void* d_ws, size_t ws_size,
                              hipStream_t stream) {
    const float* x      = (const float*)d_in[0];   // [B,S,DIM] = [NROWS,DIM]
    const float* embeds = (const float*)d_in[1];   // [QQ,KK,DIM]

    char* ws = (char*)d_ws;
    double* loss  = (double*)(ws + WS_LOSS_OFF);
    int*    idx   = (int*)   (ws + WS_IDX_OFF);
    float*  rnorm = (float*) (ws + WS_RNORM_OFF);
    float*  enorm = (float*) (ws + WS_ENORM_OFF);
    float*  res   = (float*) (ws + WS_RES_OFF);

    float* out_q      = (float*)d_out;                       // [NROWS*DIM]
    float* out_idx    = out_q + QOUT_SZ;                     // [NROWS*QQ] (indices as f32)
    float* out_scalar = out_q + QOUT_SZ + IDX_SZ;            // [1] loss

    k_zero_loss<<<1, 1, 0, stream>>>(loss);
    k_init<<<NROWS / 4, 256, 0, stream>>>((const float4*)x, (float4*)res, rnorm);
    k_enorm<<<(QQ * KK) / 4, 256, 0, stream>>>((const float4*)embeds, enorm);

    for (int q = 0; q < QQ; q++) {
        const float* embed_q = embeds + (size_t)q * KK * DIM;
        const float* enorm_q = enorm + q * KK;
        k_argmin<<<NROWS / BR, 256, 0, stream>>>(res, embed_q, enorm_q, rnorm, idx);
        k_update<<<NROWS / 4, 256, 0, stream>>>(res, embed_q, idx, rnorm, loss, out_idx, q);
    }

    k_final<<<QOUT_SZ / 4 / 256, 256, 0, stream>>>((const float4*)x, (const float4*)res,
                                                   (float4*)d_out, loss, out_scalar);
}

// Round 2
// 2212.812 us; speedup vs baseline: 1.9901x; 1.9901x over previous
//
#include <hip/hip_runtime.h>

// Problem constants: B=64, S=256, DIM=512, Q=8, K=1024
#define NROWS   16384
#define DIM     512
#define QQ      8
#define KK      1024
#define QOUT_SZ (NROWS * DIM)   // 8388608
#define IDX_SZ  (NROWS * QQ)    // 131072

// ---------------- ws layout ----------------
#define WS_LOSSP_OFF  0                                   // 512 doubles (per-block loss partials)
#define WS_RNORM_OFF  (512 * 8)                           // NROWS floats
#define WS_ENORM_OFF  (WS_RNORM_OFF + NROWS * 4)          // QQ*KK floats
#define WS_RES_OFF    (WS_ENORM_OFF + QQ * KK * 4)        // NROWS*DIM floats
#define WS_ET_OFF     (WS_RES_OFF + (size_t)NROWS * DIM * 4)  // DIM*KK floats (one quantizer, transposed)
// total ~35.8 MB

// async global->LDS, 16B per lane; LDS dest = wave-uniform base + lane*16
typedef __attribute__((address_space(3))) uint32_t lds_u32;
typedef __attribute__((address_space(1))) const uint32_t ga_u32;
#define GLOBAL_LOAD_LDS16(g, l) \
    __builtin_amdgcn_global_load_lds((ga_u32*)(g), (lds_u32*)(l), 16, 0, 0)

// rnorm[row] = sum(x[row]^2). 4 rows/block, wave per row.
__global__ __launch_bounds__(256) void k_prep(const float4* __restrict__ x4,
                                              float* __restrict__ rnorm) {
    int row  = blockIdx.x * 4 + (threadIdx.x >> 6);
    int lane = threadIdx.x & 63;
    float s = 0.f;
#pragma unroll
    for (int i = 0; i < 2; i++) {
        int c = lane + i * 64;
        float4 v = x4[row * (DIM / 4) + c];
        s += v.x * v.x + v.y * v.y + v.z * v.z + v.w * v.w;
    }
#pragma unroll
    for (int off = 32; off; off >>= 1) s += __shfl_down(s, off, 64);
    if (lane == 0) rnorm[row] = s;
}

// enorm over all QQ*KK embed rows (same reduction order as the passing run)
__global__ __launch_bounds__(256) void k_enorm(const float4* __restrict__ e4,
                                               float* __restrict__ enorm) {
    int row  = blockIdx.x * 4 + (threadIdx.x >> 6);
    int lane = threadIdx.x & 63;
    float s = 0.f;
#pragma unroll
    for (int i = 0; i < 2; i++) {
        int c = lane + i * 64;
        float4 v = e4[row * (DIM / 4) + c];
        s += v.x * v.x + v.y * v.y + v.z * v.z + v.w * v.w;
    }
#pragma unroll
    for (int off = 32; off; off >>= 1) s += __shfl_down(s, off, 64);
    if (lane == 0) enorm[row] = s;
}

// Et[d][c] = E[c][d] for one quantizer. Grid: 512 blocks (cb 32 x dt 16), 256 thr.
__global__ __launch_bounds__(256) void k_transpose(const float* __restrict__ E,
                                                   float* __restrict__ Et) {
    __shared__ float tl[32 * 33];
    int b  = blockIdx.x;
    int cb = b & 31, dt = b >> 5;
    int t  = threadIdx.x;
    {
        int cl = t >> 3, dch = t & 7;
        float4 v = *(const float4*)&E[(size_t)(cb * 32 + cl) * DIM + dt * 32 + dch * 4];
        tl[cl * 33 + dch * 4 + 0] = v.x;
        tl[cl * 33 + dch * 4 + 1] = v.y;
        tl[cl * 33 + dch * 4 + 2] = v.z;
        tl[cl * 33 + dch * 4 + 3] = v.w;
    }
    __syncthreads();
    {
        int dd = t >> 3, cc = (t & 7) * 4;
        float4 w = make_float4(tl[(cc + 0) * 33 + dd], tl[(cc + 1) * 33 + dd],
                               tl[(cc + 2) * 33 + dd], tl[(cc + 3) * 33 + dd]);
        *(float4*)&Et[(size_t)(dt * 32 + dd) * KK + cb * 32 + cc] = w;
    }
}

// Fused distance-GEMM + argmin + residual update + loss/rnorm/index.
// 512 threads (8 waves), 32 rows/block, grid = 512.
// wave = (wr<<1)|wc : wr in 0..3 -> rows wr*8..+7 ; wc in 0..1 -> code half.
// Per ct (2 tiles of 512 codes): dt loop stages Et/res tiles via global_load_lds.
__global__ __launch_bounds__(512, 4) void k_argmin_fused(
        const float* __restrict__ src,      // residual source: x (q==0) or res
        float* __restrict__ res,            // residual out
        const float* __restrict__ Et,       // [DIM][KK] transposed embeds (this q)
        const float* __restrict__ embed_q,  // [KK][DIM] original embeds (this q)
        const float* __restrict__ enorm_q,  // [KK]
        float* __restrict__ rnorm,          // [NROWS] in/out
        double* __restrict__ loss_part,     // [512]
        float* __restrict__ out_idx,        // [NROWS*QQ]
        int q) {
    __shared__ __align__(16) float es[32 * 512];   // [dd][c_local] 64 KB
    __shared__ __align__(16) float xs[32 * 32];    // [r][dd] 4 KB
    __shared__ float en_s[KK];
    __shared__ float rn_s[32];
    __shared__ float ls_d[8][8];
    __shared__ int   ls_k[8][8];
    __shared__ int   kf_s[32];
    __shared__ float ls_loss[8];

    const int tid   = threadIdx.x;
    const int wave  = tid >> 6;
    const int lid   = tid & 63;
    const int wr    = wave >> 1;
    const int wc    = wave & 1;
    const int r0blk = blockIdx.x * 32;

    for (int i = tid; i < KK; i += 512) en_s[i] = enorm_q[i];
    if (tid < 32) rn_s[tid] = rnorm[r0blk + tid];

    float bestd[8];
    int   bestk[8];
#pragma unroll
    for (int i = 0; i < 8; i++) { bestd[i] = 3.4e38f; bestk[i] = 0; }

    for (int ct = 0; ct < 2; ct++) {
        float acc[8][4];
#pragma unroll
        for (int i = 0; i < 8; i++)
#pragma unroll
            for (int j = 0; j < 4; j++) acc[i][j] = 0.f;

        for (int dt = 0; dt < 16; dt++) {
            __syncthreads();
            // stage es: 32 dd-rows x 512 codes; one wave-inst = 1KB = half a dd-row
#pragma unroll
            for (int s = 0; s < 8; s++) {
                int idx  = wave * 8 + s;        // 0..63
                int dd   = idx >> 1;
                int half = idx & 1;
                const float* g = Et + (size_t)(dt * 32 + dd) * KK + ct * 512 + half * 256 + lid * 4;
                GLOBAL_LOAD_LDS16(g, &es[dd * 512 + half * 256]);
            }
            // stage xs: 32 rows x 32 dd; waves 0..3 each cover 8 rows
            if (wave < 4) {
                int r   = wave * 8 + (lid >> 3);
                int dch = lid & 7;
                const float* g = src + (size_t)(r0blk + r) * DIM + dt * 32 + dch * 4;
                GLOBAL_LOAD_LDS16(g, &xs[wave * 8 * 32]);
            }
            __syncthreads();

#pragma unroll
            for (int v = 0; v < 8; v++) {
                float4 ev[4];
                float  xr[8][4];
#pragma unroll
                for (int m = 0; m < 4; m++)
                    ev[m] = *(const float4*)&es[(v * 4 + m) * 512 + wc * 256 + lid * 4];
#pragma unroll
                for (int i = 0; i < 8; i++) {
                    float4 t = *(const float4*)&xs[(wr * 8 + i) * 32 + v * 4];
                    xr[i][0] = t.x; xr[i][1] = t.y; xr[i][2] = t.z; xr[i][3] = t.w;
                }
#pragma unroll
                for (int m = 0; m < 4; m++) {
                    float4 e = ev[m];
#pragma unroll
                    for (int i = 0; i < 8; i++) {
                        float xm = xr[i][m];
                        acc[i][0] += xm * e.x;
                        acc[i][1] += xm * e.y;
                        acc[i][2] += xm * e.z;
                        acc[i][3] += xm * e.w;
                    }
                }
            }
        }

        // fold this 512-code tile into running best (ascending k, strict <)
        int kbase = ct * 512 + wc * 256 + lid * 4;
#pragma unroll
        for (int i = 0; i < 8; i++) {
            float rn = rn_s[wr * 8 + i];
#pragma unroll
            for (int j = 0; j < 4; j++) {
                int k   = kbase + j;
                float d = (rn + en_s[k]) - 2.0f * acc[i][j];
                if (d < bestd[i]) { bestd[i] = d; bestk[i] = k; }
            }
        }
    }

    // wave-wide lexicographic (d,k) min over 64 lanes
#pragma unroll
    for (int m = 1; m < 64; m <<= 1) {
#pragma unroll
        for (int i = 0; i < 8; i++) {
            float od = __shfl_xor(bestd[i], m, 64);
            int   ok = __shfl_xor(bestk[i], m, 64);
            if (od < bestd[i] || (od == bestd[i] && ok < bestk[i])) {
                bestd[i] = od; bestk[i] = ok;
            }
        }
    }
    if (lid == 0) {
#pragma unroll
        for (int i = 0; i < 8; i++) { ls_d[wave][i] = bestd[i]; ls_k[wave][i] = bestk[i]; }
    }
    __syncthreads();

    // combine the two code-halves, publish final index
    if (tid < 32) {
        int wrr = tid >> 3, ii = tid & 7;
        float d0 = ls_d[wrr * 2 + 0][ii], d1 = ls_d[wrr * 2 + 1][ii];
        int   k0 = ls_k[wrr * 2 + 0][ii], k1 = ls_k[wrr * 2 + 1][ii];
        int kf = (d1 < d0 || (d1 == d0 && k1 < k0)) ? k1 : k0;
        kf_s[tid] = kf;
        out_idx[(size_t)(r0blk + tid) * QQ + q] = (float)kf;
    }
    __syncthreads();

    // fused residual update: 16 threads per row, 32 floats each.
    // Mirrors reference fp ops: t = e - r; q_st = r + t; new_r = r - q_st.
    {
        int row = tid >> 4, seg = tid & 15;
        int gr  = r0blk + row;
        const float* rrow = src + (size_t)gr * DIM + seg * 32;
        const float* erow = embed_q + (size_t)kf_s[row] * DIM + seg * 32;
        float*       wrow = res + (size_t)gr * DIM + seg * 32;
        float sl = 0.f, sr = 0.f;
#pragma unroll
        for (int u = 0; u < 8; u++) {
            float4 rv = *(const float4*)(rrow + u * 4);
            float4 ev = *(const float4*)(erow + u * 4);
            float tx = ev.x - rv.x, ty = ev.y - rv.y, tz = ev.z - rv.z, tw = ev.w - rv.w;
            float qx = rv.x + tx, qy = rv.y + ty, qz = rv.z + tz, qw = rv.w + tw;
            float nx = rv.x - qx, ny = rv.y - qy, nz = rv.z - qz, nw = rv.w - qw;
            *(float4*)(wrow + u * 4) = make_float4(nx, ny, nz, nw);
            sl += tx * tx + ty * ty + tz * tz + tw * tw;
            sr += nx * nx + ny * ny + nz * nz + nw * nw;
        }
        // rnorm: reduce over the 16 lanes of this row (same wave)
        float srr = sr;
#pragma unroll
        for (int m = 1; m < 16; m <<= 1) srr += __shfl_xor(srr, m, 64);
        if (seg == 0) rnorm[gr] = srr;
        // loss: reduce over full wave, then block
        float sll = sl;
#pragma unroll
        for (int m = 1; m < 64; m <<= 1) sll += __shfl_xor(sll, m, 64);
        if (lid == 0) ls_loss[wave] = sll;
    }
    __syncthreads();
    if (tid == 0) {
        float s = 0.f;
#pragma unroll
        for (int w = 0; w < 8; w++) s += ls_loss[w];
        double cur = (q == 0) ? 0.0 : loss_part[blockIdx.x];
        loss_part[blockIdx.x] = cur + (double)s;
    }
}

// qout = x - res_final ; block 0 also reduces loss partials to the scalar
__global__ __launch_bounds__(256) void k_final(const float4* __restrict__ x4,
                                               const float4* __restrict__ res4,
                                               float4* __restrict__ out4,
                                               const double* __restrict__ loss_part,
                                               float* __restrict__ out_scalar) {
    int i = blockIdx.x * 256 + threadIdx.x;
    float4 a = x4[i], b = res4[i];
    out4[i] = make_float4(a.x - b.x, a.y - b.y, a.z - b.z, a.w - b.w);
    if (blockIdx.x == 0 && threadIdx.x < 64) {
        double s = 0.0;
#pragma unroll
        for (int j = 0; j < 8; j++) s += loss_part[threadIdx.x + 64 * j];
#pragma unroll
        for (int m = 1; m < 64; m <<= 1) s += __shfl_xor(s, m, 64);
        if (threadIdx.x == 0) out_scalar[0] = (float)(s * 2.0 / (double)QOUT_SZ);
    }
}

extern "C" void kernel_launch(void* const* d_in, const int* in_sizes, int n_in,
                              void* d_out, int out_size, void* d_ws, size_t ws_size,
                              hipStream_t stream) {
    const float* x      = (const float*)d_in[0];   // [NROWS][DIM]
    const float* embeds = (const float*)d_in[1];   // [QQ][KK][DIM]

    char*   ws        = (char*)d_ws;
    double* loss_part = (double*)(ws + WS_LOSSP_OFF);
    float*  rnorm     = (float*) (ws + WS_RNORM_OFF);
    float*  enorm     = (float*) (ws + WS_ENORM_OFF);
    float*  res       = (float*) (ws + WS_RES_OFF);
    float*  Et        = (float*) (ws + WS_ET_OFF);

    float* out_q      = (float*)d_out;
    float* out_idx    = out_q + QOUT_SZ;
    float* out_scalar = out_q + QOUT_SZ + IDX_SZ;

    k_prep <<<NROWS / 4, 256, 0, stream>>>((const float4*)x, rnorm);
    k_enorm<<<(QQ * KK) / 4, 256, 0, stream>>>((const float4*)embeds, enorm);

    for (int q = 0; q < QQ; q++) {
        const float* embed_q = embeds + (size_t)q * KK * DIM;
        const float* enorm_q = enorm + q * KK;
        k_transpose<<<512, 256, 0, stream>>>(embed_q, Et);
        const float* src = (q == 0) ? x : res;
        k_argmin_fused<<<512, 512, 0, stream>>>(src, res, Et, embed_q, enorm_q,
                                                rnorm, loss_part, out_idx, q);
    }

    k_final<<<QOUT_SZ / 4 / 256, 256, 0, stream>>>((const float4*)x, (const float4*)res,
                                                   (float4*)d_out, loss_part, out_scalar);
}